// Round 23
// baseline (775.806 us; speedup 1.0000x reference)
//
#include <hip/hip_runtime.h>
#include <math.h>

// Problem constants
#define NROW 8192   // B*T
#define DIM  512
#define TT   2048
#define HH   4
#define DH   128
#define GG   2025   // GH*GW
#define KP   2048   // GG padded to 2048 for MFMA K
#define SS   2048
#define KTOP 40

typedef __attribute__((ext_vector_type(8))) short short8v;   // 8 bf16
typedef __attribute__((ext_vector_type(4))) float f32x4;

__device__ __forceinline__ unsigned short f2bf(float f) {   // RNE f32->bf16
    unsigned int u = __float_as_uint(f);
    u += 0x7fffu + ((u >> 16) & 1u);
    return (unsigned short)(u >> 16);
}
__device__ __forceinline__ float bf2f(unsigned short b) {
    return __uint_as_float(((unsigned int)b) << 16);
}

// ---------------------------------------------------------------------------
// embed gather + layernorm; xn emitted as 2-plane bf16 split (round 18)
// ---------------------------------------------------------------------------
__global__ __launch_bounds__(256) void k_embed_ln(
    const int* __restrict__ tokens, const float* __restrict__ table,
    const float* __restrict__ g, const float* __restrict__ b,
    float* __restrict__ x,
    unsigned short* __restrict__ X0, unsigned short* __restrict__ X1)
{
    __shared__ float red[4];
    const int row = blockIdx.x;
    const int tid = threadIdx.x;
    const float* src = table + (size_t)tokens[row] * DIM;
    float v0 = src[tid], v1 = src[tid + 256];

    float s = v0 + v1;
    for (int off = 32; off; off >>= 1) s += __shfl_xor(s, off, 64);
    if ((tid & 63) == 0) red[tid >> 6] = s;
    __syncthreads();
    float mean = (red[0] + red[1] + red[2] + red[3]) * (1.0f / 512.0f);
    __syncthreads();

    float d0 = v0 - mean, d1 = v1 - mean;
    float ss = d0 * d0 + d1 * d1;
    for (int off = 32; off; off >>= 1) ss += __shfl_xor(ss, off, 64);
    if ((tid & 63) == 0) red[tid >> 6] = ss;
    __syncthreads();
    float var = (red[0] + red[1] + red[2] + red[3]) * (1.0f / 512.0f);
    float rs = 1.0f / sqrtf(var + 1e-5f);

    size_t base = (size_t)row * DIM;
    x[base + tid]       = v0;
    x[base + tid + 256] = v1;
    float xn0 = d0 * rs * g[tid] + b[tid];
    float xn1 = d1 * rs * g[tid + 256] + b[tid + 256];
    {
        unsigned short h0 = f2bf(xn0);
        X0[base + tid] = h0; X1[base + tid] = f2bf(xn0 - bf2f(h0));
    }
    {
        unsigned short h0 = f2bf(xn1);
        X0[base + tid + 256] = h0; X1[base + tid + 256] = f2bf(xn1 - bf2f(h0));
    }
}

// ---------------------------------------------------------------------------
// f32 GEMM 128x128/8x8 with register prefetch (round 13/18/21, passed)
// ---------------------------------------------------------------------------
enum { EPI_BIAS = 0, EPI_SIGMOID = 1, EPI_GATERES = 2, EPI_GELU = 3, EPI_NONE = 4, EPI_QKVG = 5 };

template<int EPI, int KCH = 0>
__global__ __launch_bounds__(256) void k_gemm_f32(
    const float* __restrict__ A, const float* __restrict__ B,
    const float* __restrict__ bias, float* __restrict__ C,
    int M, int N, int K,
    const float* __restrict__ resid, const float* __restrict__ gate, int gstride)
{
    __shared__ float As[16][132];
    __shared__ float Bs[16][132];
    const int tid = threadIdx.x;
    const int tx = tid & 15, ty = tid >> 4;
    const int bm = blockIdx.y * 128, bn = blockIdx.x * 128;
    float acc[8][8] = {};

    int kbeg = 0, kend = K;
    float* Cw = C;
    if (KCH > 0) {
        kbeg = blockIdx.z * KCH;
        kend = min(kbeg + KCH, K);
        Cw = C + (size_t)blockIdx.z * M * N;
    }

    const int a_m = tid >> 2;
    const int a_c = (tid & 3) * 4;
    const int b_r = tid >> 5;
    const int b_n = (tid & 31) * 4;

    const float* Arow0 = A + (size_t)(bm + a_m) * K + a_c;
    const float* Arow1 = A + (size_t)(bm + a_m + 64) * K + a_c;
    const float* Brow0 = B + (size_t)b_r * N + bn + b_n;
    const float* Brow1 = B + (size_t)(b_r + 8) * N + bn + b_n;

    float4 av0 = *(const float4*)(Arow0 + kbeg);
    float4 av1 = *(const float4*)(Arow1 + kbeg);
    float4 bv0 = *(const float4*)(Brow0 + (size_t)kbeg * N);
    float4 bv1 = *(const float4*)(Brow1 + (size_t)kbeg * N);

    for (int k0 = kbeg; k0 < kend; k0 += 16) {
        __syncthreads();
        As[a_c + 0][a_m] = av0.x; As[a_c + 1][a_m] = av0.y;
        As[a_c + 2][a_m] = av0.z; As[a_c + 3][a_m] = av0.w;
        As[a_c + 0][a_m + 64] = av1.x; As[a_c + 1][a_m + 64] = av1.y;
        As[a_c + 2][a_m + 64] = av1.z; As[a_c + 3][a_m + 64] = av1.w;
        *(float4*)&Bs[b_r][b_n]     = bv0;
        *(float4*)&Bs[b_r + 8][b_n] = bv1;
        __syncthreads();
        if (k0 + 16 < kend) {
            av0 = *(const float4*)(Arow0 + k0 + 16);
            av1 = *(const float4*)(Arow1 + k0 + 16);
            bv0 = *(const float4*)(Brow0 + (size_t)(k0 + 16) * N);
            bv1 = *(const float4*)(Brow1 + (size_t)(k0 + 16) * N);
        }
#pragma unroll
        for (int kk = 0; kk < 16; ++kk) {
            float4 a0 = *(const float4*)&As[kk][ty * 4];
            float4 a1 = *(const float4*)&As[kk][64 + ty * 4];
            float4 b0 = *(const float4*)&Bs[kk][tx * 4];
            float4 b1 = *(const float4*)&Bs[kk][64 + tx * 4];
            float av[8] = {a0.x, a0.y, a0.z, a0.w, a1.x, a1.y, a1.z, a1.w};
            float bv[8] = {b0.x, b0.y, b0.z, b0.w, b1.x, b1.y, b1.z, b1.w};
#pragma unroll
            for (int i = 0; i < 8; ++i)
#pragma unroll
                for (int j = 0; j < 8; ++j)
                    acc[i][j] = fmaf(av[i], bv[j], acc[i][j]);
        }
    }

#pragma unroll
    for (int i = 0; i < 8; ++i) {
        int m = bm + 4 * ty + (i & 3) + (i >> 2) * 64;
#pragma unroll
        for (int half = 0; half < 2; ++half) {
            int n0 = bn + 4 * tx + half * 64;
            size_t idx = (size_t)m * N + n0;
            float4 o;
            float* oo = (float*)&o;
#pragma unroll
            for (int j = 0; j < 4; ++j) {
                float t = acc[i][half * 4 + j];
                if (EPI != EPI_NONE && KCH == 0) t += bias[n0 + j];
                float r;
                if (KCH > 0)                 r = t;
                else if (EPI == EPI_SIGMOID) r = 1.0f / (1.0f + expf(-t));
                else if (EPI == EPI_GATERES) r = resid[idx + j] + gate[(size_t)m * gstride + n0 + j] * t;
                else if (EPI == EPI_GELU)    r = 0.5f * t * (1.0f + erff(t * 0.70710678118654752440f));
                else                         r = t;
                oo[j] = r;
            }
            *(float4*)&Cw[idx] = o;
        }
    }
}

// ---------------------------------------------------------------------------
// gelu GEMM writing 2-plane bf16 split directly (round 18/21, passed)
// ---------------------------------------------------------------------------
__global__ __launch_bounds__(256) void k_gemm_gelu2(
    const float* __restrict__ A, const float* __restrict__ B,
    const float* __restrict__ bias,
    unsigned short* __restrict__ P0, unsigned short* __restrict__ P1,
    int M, int N, int K)
{
    __shared__ float As[16][132];
    __shared__ float Bs[16][132];
    const int tid = threadIdx.x;
    const int tx = tid & 15, ty = tid >> 4;
    const int bm = blockIdx.y * 128, bn = blockIdx.x * 128;
    float acc[8][8] = {};

    const int a_m = tid >> 2;
    const int a_c = (tid & 3) * 4;
    const int b_r = tid >> 5;
    const int b_n = (tid & 31) * 4;

    const float* Arow0 = A + (size_t)(bm + a_m) * K + a_c;
    const float* Arow1 = A + (size_t)(bm + a_m + 64) * K + a_c;
    const float* Brow0 = B + (size_t)b_r * N + bn + b_n;
    const float* Brow1 = B + (size_t)(b_r + 8) * N + bn + b_n;

    float4 av0 = *(const float4*)(Arow0);
    float4 av1 = *(const float4*)(Arow1);
    float4 bv0 = *(const float4*)(Brow0);
    float4 bv1 = *(const float4*)(Brow1);

    for (int k0 = 0; k0 < K; k0 += 16) {
        __syncthreads();
        As[a_c + 0][a_m] = av0.x; As[a_c + 1][a_m] = av0.y;
        As[a_c + 2][a_m] = av0.z; As[a_c + 3][a_m] = av0.w;
        As[a_c + 0][a_m + 64] = av1.x; As[a_c + 1][a_m + 64] = av1.y;
        As[a_c + 2][a_m + 64] = av1.z; As[a_c + 3][a_m + 64] = av1.w;
        *(float4*)&Bs[b_r][b_n]     = bv0;
        *(float4*)&Bs[b_r + 8][b_n] = bv1;
        __syncthreads();
        if (k0 + 16 < K) {
            av0 = *(const float4*)(Arow0 + k0 + 16);
            av1 = *(const float4*)(Arow1 + k0 + 16);
            bv0 = *(const float4*)(Brow0 + (size_t)(k0 + 16) * N);
            bv1 = *(const float4*)(Brow1 + (size_t)(k0 + 16) * N);
        }
#pragma unroll
        for (int kk = 0; kk < 16; ++kk) {
            float4 a0 = *(const float4*)&As[kk][ty * 4];
            float4 a1 = *(const float4*)&As[kk][64 + ty * 4];
            float4 b0 = *(const float4*)&Bs[kk][tx * 4];
            float4 b1 = *(const float4*)&Bs[kk][64 + tx * 4];
            float av[8] = {a0.x, a0.y, a0.z, a0.w, a1.x, a1.y, a1.z, a1.w};
            float bv[8] = {b0.x, b0.y, b0.z, b0.w, b1.x, b1.y, b1.z, b1.w};
#pragma unroll
            for (int i = 0; i < 8; ++i)
#pragma unroll
                for (int j = 0; j < 8; ++j)
                    acc[i][j] = fmaf(av[i], bv[j], acc[i][j]);
        }
    }

#pragma unroll
    for (int i = 0; i < 8; ++i) {
        int m = bm + 4 * ty + (i & 3) + (i >> 2) * 64;
#pragma unroll
        for (int half = 0; half < 2; ++half) {
            int n0 = bn + 4 * tx + half * 64;
            ushort4 o0, o1;
            unsigned short* q0 = (unsigned short*)&o0;
            unsigned short* q1 = (unsigned short*)&o1;
#pragma unroll
            for (int j = 0; j < 4; ++j) {
                float t = acc[i][half * 4 + j] + bias[n0 + j];
                float r = 0.5f * t * (1.0f + erff(t * 0.70710678118654752440f));
                unsigned short h0 = f2bf(r);
                q0[j] = h0; q1[j] = f2bf(r - bf2f(h0));
            }
            size_t idx = (size_t)m * N + n0;
            *(ushort4*)&P0[idx] = o0;
            *(ushort4*)&P1[idx] = o1;
        }
    }
}

// ---------------------------------------------------------------------------
// pack wq|wk|wv|wg -> wpack (512x2048), biases -> bpack (round 18)
// ---------------------------------------------------------------------------
__global__ __launch_bounds__(256) void k_pack_qkvg(
    const float* __restrict__ wq, const float* __restrict__ wk,
    const float* __restrict__ wv, const float* __restrict__ wg,
    const float* __restrict__ bq, const float* __restrict__ bk,
    const float* __restrict__ bv, const float* __restrict__ bg,
    float* __restrict__ wpack, float* __restrict__ bpack)
{
    const int idx = blockIdx.x * 256 + threadIdx.x;
    const int k = idx >> 11, n = idx & 2047;
    const int sel = n >> 9, nn = n & 511;
    const float* w = (sel == 0) ? wq : (sel == 1) ? wk : (sel == 2) ? wv : wg;
    wpack[idx] = w[(size_t)k * 512 + nn];
    if (idx < 2048) {
        const float* bb = (sel == 0) ? bq : (sel == 1) ? bk : (sel == 2) ? bv : bg;
        bpack[idx] = bb[nn];
    }
}

// ---------------------------------------------------------------------------
// banded attention over packed QKVG (round 18)
// ---------------------------------------------------------------------------
__global__ __launch_bounds__(256) void k_attn(
    const float* __restrict__ qkvg, float* __restrict__ out)
{
    const int w    = (blockIdx.x << 2) + (threadIdx.x >> 6);
    const int lane = threadIdx.x & 63;
    const int h = w & 3;
    const int t = (w >> 2) & 2047;
    const int b = w >> 13;
    const size_t qb = ((size_t)(b * TT + t)) * 2048 + h * DH;
    const float q0 = qkvg[qb + lane], q1 = qkvg[qb + 64 + lane];

    float s[11];
#pragma unroll
    for (int o = 0; o < 11; ++o) {
        int pos = t + o - 5;
        bool valid = (pos >= 0 && pos < TT);
        float p = 0.0f;
        if (valid) {
            size_t kb = ((size_t)(b * TT + pos)) * 2048 + 512 + h * DH;
            p = q0 * qkvg[kb + lane] + q1 * qkvg[kb + 64 + lane];
        }
        for (int off = 32; off; off >>= 1) p += __shfl_xor(p, off, 64);
        s[o] = valid ? p / sqrtf(128.0f) : -1e9f;
    }
    float m = s[0];
#pragma unroll
    for (int o = 1; o < 11; ++o) m = fmaxf(m, s[o]);
    float e[11], sum = 0.0f;
#pragma unroll
    for (int o = 0; o < 11; ++o) { e[o] = expf(s[o] - m); sum += e[o]; }

    float o0 = 0.0f, o1 = 0.0f;
#pragma unroll
    for (int o = 0; o < 11; ++o) {
        int pos = t + o - 5;
        if (pos < 0 || pos >= TT) continue;
        float a = e[o] / sum;
        size_t vb = ((size_t)(b * TT + pos)) * 2048 + 1024 + h * DH;
        o0 = fmaf(a, qkvg[vb + lane], o0);
        o1 = fmaf(a, qkvg[vb + 64 + lane], o1);
    }
    const size_t ob = ((size_t)(b * TT + t)) * DIM + h * DH;
    out[ob + lane]      = o0;
    out[ob + 64 + lane] = o1;
}

// ---------------------------------------------------------------------------
// wf2f conv (KP rows; rows >= GG zero), bias_c (round 18/21)
// ---------------------------------------------------------------------------
__global__ __launch_bounds__(256) void k_conv_wf(
    const float* __restrict__ wf, float* __restrict__ wf2f)
{
    __shared__ float w[25];
    const int qq = blockIdx.x;
    if (qq >= GG) {
        for (int s = threadIdx.x; s < SS; s += 256)
            wf2f[(size_t)qq * SS + s] = 0.0f;
        return;
    }
    const int y = qq / 45, x = qq % 45;
    if (threadIdx.x < 25) {
        int ki = threadIdx.x / 5, kj = threadIdx.x % 5;
        double gi = exp(-0.5 * (double)((ki - 2) * (ki - 2)));
        double gj = exp(-0.5 * (double)((kj - 2) * (kj - 2)));
        double Z  = 1.0 + 2.0 * exp(-0.5) + 2.0 * exp(-2.0);
        w[threadIdx.x] = (float)(gi * gj / (Z * Z));
    }
    __syncthreads();
    for (int s = threadIdx.x; s < SS; s += 256) {
        double acc = 0.0;
#pragma unroll
        for (int dy = -2; dy <= 2; ++dy) {
            int yy = y + dy;
            if (yy < 0 || yy >= 45) continue;
#pragma unroll
            for (int dx = -2; dx <= 2; ++dx) {
                int xx2 = x + dx;
                if (xx2 < 0 || xx2 >= 45) continue;
                acc = fma((double)w[(dy + 2) * 5 + (dx + 2)],
                          (double)wf[(size_t)(yy * 45 + xx2) * SS + s], acc);
            }
        }
        wf2f[(size_t)qq * SS + s] = (float)acc;
    }
}

__global__ __launch_bounds__(256) void k_bias_c(
    const float* __restrict__ b2, const float* __restrict__ wf2f,
    float* __restrict__ c)
{
    const int s = blockIdx.x * 4 + (threadIdx.x >> 6);
    const int lane = threadIdx.x & 63;
    double acc = 0.0;
    for (int qq = lane; qq < GG; qq += 64)
        acc = fma((double)b2[qq], (double)wf2f[(size_t)qq * SS + s], acc);
    for (int off = 32; off; off >>= 1) acc += __shfl_xor(acc, off, 64);
    if (lane == 0) c[s] = (float)acc;
}

// w2 (1024xGG) -> 2-plane bf16 (1024xKP), cols >= GG zero
__global__ __launch_bounds__(256) void k_splitw2(
    const float* __restrict__ w2, unsigned short* __restrict__ P0,
    unsigned short* __restrict__ P1)
{
    const int idx = blockIdx.x * 256 + threadIdx.x;   // 1024*KP
    const int m = idx >> 11, p = idx & (KP - 1);
    float v = (p < GG) ? w2[(size_t)m * GG + p] : 0.0f;
    unsigned short h0 = f2bf(v);
    P0[idx] = h0; P1[idx] = f2bf(v - bf2f(h0));
}

// ---------------------------------------------------------------------------
// transpose + 2-plane split: W (KxN f32) -> planes (NxK bf16)  (round 18/21)
// ---------------------------------------------------------------------------
__global__ __launch_bounds__(256) void k_tsplit2(
    const float* __restrict__ W, unsigned short* __restrict__ T0,
    unsigned short* __restrict__ T1, int K, int N)
{
    __shared__ float t[32][33];
    const int tx = threadIdx.x & 31, ty = threadIdx.x >> 5;
    const int n0 = blockIdx.x * 32, k0 = blockIdx.y * 32;
#pragma unroll
    for (int p = 0; p < 4; ++p)
        t[ty + 8 * p][tx] = W[(size_t)(k0 + ty + 8 * p) * N + n0 + tx];
    __syncthreads();
#pragma unroll
    for (int p = 0; p < 4; ++p) {
        float v = t[tx][ty + 8 * p];
        size_t o = (size_t)(n0 + ty + 8 * p) * K + k0 + tx;
        unsigned short h0 = f2bf(v);
        T0[o] = h0; T1[o] = f2bf(v - bf2f(h0));
    }
}

// ---------------------------------------------------------------------------
// bf16x4 MFMA GEMM (validated r18/r21) + ROUND 23: XOR granule swizzle on
// LDS staging/reads. granule' = granule ^ ((row>>3)&3) — bijective per row;
// breaks the 4-way bank conflict of the 80B row stride (period-8 rows).
// Semantically identical (pure address permutation).
// ---------------------------------------------------------------------------
template<int EPI>
__global__ __launch_bounds__(256) void k_gemm_bf16x4(
    const unsigned short* __restrict__ A0, const unsigned short* __restrict__ A1,
    const unsigned short* __restrict__ B0, const unsigned short* __restrict__ B1,
    const float* __restrict__ bias, float* __restrict__ C, int M, int N, int K)
{
    __shared__ unsigned short As[2][128][40];
    __shared__ unsigned short Bs[2][128][40];
    const int tid = threadIdx.x, lane = tid & 63, wid = tid >> 6;
    const int wm = wid >> 1, wn = wid & 1;
    const int bm = blockIdx.y * 128, bn = blockIdx.x * 128;
    const int lm = lane & 15, lk = lane >> 4;

    f32x4 acc[4][4] = {};

    const int sr = tid >> 1, sc = (tid & 1) * 16;
    const int swzW = (sr >> 3) & 3;                   // write-side row swizzle
    const int g0 = sc >> 3;                           // granule 0 or 2
    const int c0 = ((g0    ) ^ swzW) << 3;
    const int c1 = ((g0 + 1) ^ swzW) << 3;
    const unsigned short* Ap[2] = {A0, A1};
    const unsigned short* Bp[2] = {B0, B1};

    for (int k0 = 0; k0 < K; k0 += 32) {
        const size_t ga = (size_t)(bm + sr) * K + k0 + sc;
        const size_t gb = (size_t)(bn + sr) * K + k0 + sc;
        __syncthreads();
#pragma unroll
        for (int pl = 0; pl < 2; ++pl) {
            *(uint4*)&As[pl][sr][c0] = *(const uint4*)&Ap[pl][ga];
            *(uint4*)&As[pl][sr][c1] = *(const uint4*)&Ap[pl][ga + 8];
            *(uint4*)&Bs[pl][sr][c0] = *(const uint4*)&Bp[pl][gb];
            *(uint4*)&Bs[pl][sr][c1] = *(const uint4*)&Bp[pl][gb + 8];
        }
        __syncthreads();

        short8v af[2][4], bf[2][4];
#pragma unroll
        for (int pl = 0; pl < 2; ++pl)
#pragma unroll
            for (int i = 0; i < 4; ++i) {
                const int ra = wm * 64 + i * 16 + lm;
                const int rb = wn * 64 + i * 16 + lm;
                const int ca = (lk ^ ((ra >> 3) & 3)) << 3;
                const int cb = (lk ^ ((rb >> 3) & 3)) << 3;
                af[pl][i] = *(const short8v*)&As[pl][ra][ca];
                bf[pl][i] = *(const short8v*)&Bs[pl][rb][cb];
            }
#pragma unroll
        for (int i = 0; i < 4; ++i)
#pragma unroll
            for (int j = 0; j < 4; ++j) {
                acc[i][j] = __builtin_amdgcn_mfma_f32_16x16x32_bf16(af[0][i], bf[0][j], acc[i][j], 0, 0, 0);
                acc[i][j] = __builtin_amdgcn_mfma_f32_16x16x32_bf16(af[0][i], bf[1][j], acc[i][j], 0, 0, 0);
                acc[i][j] = __builtin_amdgcn_mfma_f32_16x16x32_bf16(af[1][i], bf[0][j], acc[i][j], 0, 0, 0);
                acc[i][j] = __builtin_amdgcn_mfma_f32_16x16x32_bf16(af[1][i], bf[1][j], acc[i][j], 0, 0, 0);
            }
    }

#pragma unroll
    for (int i = 0; i < 4; ++i) {
        const int row0 = bm + wm * 64 + i * 16 + lk * 4;
#pragma unroll
        for (int j = 0; j < 4; ++j) {
            const int col = bn + wn * 64 + j * 16 + lm;
            const float bb = (EPI == EPI_NONE) ? 0.0f : bias[col];
#pragma unroll
            for (int r = 0; r < 4; ++r) {
                float t = acc[i][j][r] + bb;
                if (EPI == EPI_QKVG && col >= 1536) t = 1.0f / (1.0f + expf(-t));
                C[(size_t)(row0 + r) * N + col] = t;
            }
        }
    }
}

// ---------------------------------------------------------------------------
// top-40 one-hot, one wave per row (validated round 16)
// ---------------------------------------------------------------------------
__global__ __launch_bounds__(256) void k_topk(
    const float* __restrict__ scores, float* __restrict__ sdr)
{
    __shared__ float vals[4][64 * 33];
    const int wv = threadIdx.x >> 6;
    const int lane = threadIdx.x & 63;
    const int row = (blockIdx.x << 2) + wv;
    const float* srow = scores + (size_t)row * SS;
    float* drow = sdr + (size_t)row * SS;
    float* my = &vals[wv][lane * 33];

    float lmax = -INFINITY; int lidx = 0x7fffffff;
#pragma unroll
    for (int j = 0; j < 32; ++j) {
        const int gi = j * 64 + lane;
        float vvv = srow[gi];
        drow[gi] = 0.0f;
        vals[wv][lane * 33 + j] = vvv;
        if (vvv > lmax) { lmax = vvv; lidx = gi; }
    }

    for (int it = 0; it < KTOP; ++it) {
        float bv = lmax; int bi = lidx;
#pragma unroll
        for (int off = 32; off; off >>= 1) {
            float ov = __shfl_xor(bv, off, 64);
            int   oi = __shfl_xor(bi, off, 64);
            if (ov > bv || (ov == bv && oi < bi)) { bv = ov; bi = oi; }
        }
        if ((bi & 63) == lane) {
            drow[bi] = 1.0f;
            my[bi >> 6] = -INFINITY;
            lmax = -INFINITY; lidx = 0x7fffffff;
#pragma unroll
            for (int j = 0; j < 32; ++j) {
                float vvv = my[j];
                if (vvv > lmax) { lmax = vvv; lidx = j * 64 + lane; }
            }
        }
    }
}

// ---------------------------------------------------------------------------
// Buffer plan = round 21 (passed), unchanged.
// ---------------------------------------------------------------------------
extern "C" void kernel_launch(void* const* d_in, const int* in_sizes, int n_in,
                              void* d_out, int out_size, void* d_ws, size_t ws_size,
                              hipStream_t stream)
{
    (void)d_ws; (void)ws_size; (void)in_sizes; (void)n_in; (void)out_size;

    const int*   tokens = (const int*)d_in[0];
    const float* table  = (const float*)d_in[1];
    const float* ln_g   = (const float*)d_in[2];
    const float* ln_b   = (const float*)d_in[3];
    const float* wq = (const float*)d_in[4];  const float* bq = (const float*)d_in[5];
    const float* wk = (const float*)d_in[6];  const float* bk = (const float*)d_in[7];
    const float* wv = (const float*)d_in[8];  const float* bv = (const float*)d_in[9];
    const float* wo = (const float*)d_in[10]; const float* bo = (const float*)d_in[11];
    const float* wg = (const float*)d_in[12]; const float* bg = (const float*)d_in[13];
    const float* w1 = (const float*)d_in[14]; const float* b1 = (const float*)d_in[15];
    const float* w2 = (const float*)d_in[16]; const float* b2 = (const float*)d_in[17];
    const float* wf = (const float*)d_in[18];

    const size_t SZ  = (size_t)NROW * DIM;         // 4,194,304 floats
    const size_t HSZ = SZ / 2;
    const size_t MEG = 1u << 20;                   // 1,048,576 floats
    float* slot0 = (float*)d_out;
    float* slot1 = slot0 + (size_t)NROW * SS;

    float* x     = slot0;
    unsigned short* Xn0 = (unsigned short*)(slot0 + 3 * SZ);
    unsigned short* Xn1 = (unsigned short*)(slot0 + 3 * SZ + HSZ);
    float* wpack = slot0 + 2 * SZ + HSZ;
    float* bpack = wpack + MEG;
    unsigned short* Wq0 = (unsigned short*)(slot0 + SZ);
    unsigned short* Wq1 = (unsigned short*)(slot0 + SZ + MEG / 2);
    float* attn  = slot0 + SZ;
    float* ctx   = slot0 + 2 * SZ;
    unsigned short* A0 = (unsigned short*)(slot0);
    unsigned short* A1 = (unsigned short*)(slot0 + SZ);
    unsigned short* B0 = (unsigned short*)(slot0 + 2 * SZ);
    unsigned short* B1 = (unsigned short*)(slot0 + 2 * SZ + MEG);
    float* cvec = slot0 + 3 * SZ;

    float* qkvg  = slot1;
    float* wf2f  = slot1;                          // KPx2048 = SZ floats
    unsigned short* wfT0 = (unsigned short*)(slot1 + SZ);
    unsigned short* wfT1 = (unsigned short*)(slot1 + SZ + 2 * MEG);
    unsigned short* w2p0 = (unsigned short*)(slot1 + 2 * SZ);
    unsigned short* w2p1 = (unsigned short*)(slot1 + 2 * SZ + MEG);
    float* Wf    = slot1 + 3 * SZ;                 // 1024x2048 f32
    float* scores = slot1;
    float* sdr    = slot0;

    dim3 blk(256);

    k_embed_ln<<<NROW, blk, 0, stream>>>(tokens, table, ln_g, ln_b, x, Xn0, Xn1);
    k_pack_qkvg<<<4096, blk, 0, stream>>>(wq, wk, wv, wg, bq, bk, bv, bg, wpack, bpack);
    k_tsplit2               <<<dim3(64, 16), blk, 0, stream>>>(wpack, Wq0, Wq1, 512, 2048);
    k_gemm_bf16x4<EPI_QKVG> <<<dim3(16, 64), blk, 0, stream>>>(Xn0, Xn1, Wq0, Wq1, bpack, qkvg, NROW, 2048, DIM);
    k_attn                  <<<NROW, blk, 0, stream>>>(qkvg, attn);
    k_gemm_f32<EPI_GATERES> <<<dim3(4, 64), blk, 0, stream>>>(attn, wo, bo, ctx, NROW, DIM, DIM, x, qkvg + 1536, 2048);
    k_gemm_gelu2            <<<dim3(8, 64), blk, 0, stream>>>(ctx, w1, b1, A0, A1, NROW, 2 * DIM, DIM);
    k_conv_wf               <<<KP,   blk, 0, stream>>>(wf, wf2f);
    k_splitw2               <<<(1024 * KP) / 256, blk, 0, stream>>>(w2, w2p0, w2p1);
    k_tsplit2               <<<dim3(64, 64), blk, 0, stream>>>(wf2f, wfT0, wfT1, KP, 2048);
    k_gemm_bf16x4<EPI_NONE> <<<dim3(16, 8), blk, 0, stream>>>(w2p0, w2p1, wfT0, wfT1, cvec, Wf, 1024, SS, KP);
    k_bias_c                <<<SS / 4, blk, 0, stream>>>(b2, wf2f, cvec);
    k_tsplit2               <<<dim3(64, 32), blk, 0, stream>>>(Wf, B0, B1, 1024, SS);
    k_gemm_bf16x4<EPI_BIAS> <<<dim3(16, 64), blk, 0, stream>>>(A0, A1, B0, B1, cvec, scores, NROW, SS, 1024);
    k_topk                  <<<2048, blk, 0, stream>>>(scores, sdr);
}

// Round 24
// 770.337 us; speedup vs baseline: 1.0071x; 1.0071x over previous
//
#include <hip/hip_runtime.h>
#include <math.h>

// Problem constants
#define NROW 8192   // B*T
#define DIM  512
#define TT   2048
#define HH   4
#define DH   128
#define GG   2025   // GH*GW
#define KP   2048   // GG padded to 2048 for MFMA K
#define SS   2048
#define KTOP 40

typedef __attribute__((ext_vector_type(8))) short short8v;   // 8 bf16
typedef __attribute__((ext_vector_type(4))) float f32x4;

__device__ __forceinline__ unsigned short f2bf(float f) {   // RNE f32->bf16
    unsigned int u = __float_as_uint(f);
    u += 0x7fffu + ((u >> 16) & 1u);
    return (unsigned short)(u >> 16);
}
__device__ __forceinline__ float bf2f(unsigned short b) {
    return __uint_as_float(((unsigned int)b) << 16);
}

// ---------------------------------------------------------------------------
// embed gather + layernorm; xn emitted as 2-plane bf16 split (validated r18+)
// ---------------------------------------------------------------------------
__global__ __launch_bounds__(256) void k_embed_ln(
    const int* __restrict__ tokens, const float* __restrict__ table,
    const float* __restrict__ g, const float* __restrict__ b,
    float* __restrict__ x,
    unsigned short* __restrict__ X0, unsigned short* __restrict__ X1)
{
    __shared__ float red[4];
    const int row = blockIdx.x;
    const int tid = threadIdx.x;
    const float* src = table + (size_t)tokens[row] * DIM;
    float v0 = src[tid], v1 = src[tid + 256];

    float s = v0 + v1;
    for (int off = 32; off; off >>= 1) s += __shfl_xor(s, off, 64);
    if ((tid & 63) == 0) red[tid >> 6] = s;
    __syncthreads();
    float mean = (red[0] + red[1] + red[2] + red[3]) * (1.0f / 512.0f);
    __syncthreads();

    float d0 = v0 - mean, d1 = v1 - mean;
    float ss = d0 * d0 + d1 * d1;
    for (int off = 32; off; off >>= 1) ss += __shfl_xor(ss, off, 64);
    if ((tid & 63) == 0) red[tid >> 6] = ss;
    __syncthreads();
    float var = (red[0] + red[1] + red[2] + red[3]) * (1.0f / 512.0f);
    float rs = 1.0f / sqrtf(var + 1e-5f);

    size_t base = (size_t)row * DIM;
    x[base + tid]       = v0;
    x[base + tid + 256] = v1;
    float xn0 = d0 * rs * g[tid] + b[tid];
    float xn1 = d1 * rs * g[tid + 256] + b[tid + 256];
    {
        unsigned short h0 = f2bf(xn0);
        X0[base + tid] = h0; X1[base + tid] = f2bf(xn0 - bf2f(h0));
    }
    {
        unsigned short h0 = f2bf(xn1);
        X0[base + tid + 256] = h0; X1[base + tid + 256] = f2bf(xn1 - bf2f(h0));
    }
}

// ---------------------------------------------------------------------------
// f32 GEMM 128x128/8x8 with register prefetch (validated rounds 13/18/21)
// ---------------------------------------------------------------------------
enum { EPI_BIAS = 0, EPI_SIGMOID = 1, EPI_GATERES = 2, EPI_GELU = 3, EPI_NONE = 4, EPI_QKVG = 5 };

template<int EPI, int KCH = 0>
__global__ __launch_bounds__(256) void k_gemm_f32(
    const float* __restrict__ A, const float* __restrict__ B,
    const float* __restrict__ bias, float* __restrict__ C,
    int M, int N, int K,
    const float* __restrict__ resid, const float* __restrict__ gate, int gstride)
{
    __shared__ float As[16][132];
    __shared__ float Bs[16][132];
    const int tid = threadIdx.x;
    const int tx = tid & 15, ty = tid >> 4;
    const int bm = blockIdx.y * 128, bn = blockIdx.x * 128;
    float acc[8][8] = {};

    int kbeg = 0, kend = K;
    float* Cw = C;
    if (KCH > 0) {
        kbeg = blockIdx.z * KCH;
        kend = min(kbeg + KCH, K);
        Cw = C + (size_t)blockIdx.z * M * N;
    }

    const int a_m = tid >> 2;
    const int a_c = (tid & 3) * 4;
    const int b_r = tid >> 5;
    const int b_n = (tid & 31) * 4;

    const float* Arow0 = A + (size_t)(bm + a_m) * K + a_c;
    const float* Arow1 = A + (size_t)(bm + a_m + 64) * K + a_c;
    const float* Brow0 = B + (size_t)b_r * N + bn + b_n;
    const float* Brow1 = B + (size_t)(b_r + 8) * N + bn + b_n;

    float4 av0 = *(const float4*)(Arow0 + kbeg);
    float4 av1 = *(const float4*)(Arow1 + kbeg);
    float4 bv0 = *(const float4*)(Brow0 + (size_t)kbeg * N);
    float4 bv1 = *(const float4*)(Brow1 + (size_t)kbeg * N);

    for (int k0 = kbeg; k0 < kend; k0 += 16) {
        __syncthreads();
        As[a_c + 0][a_m] = av0.x; As[a_c + 1][a_m] = av0.y;
        As[a_c + 2][a_m] = av0.z; As[a_c + 3][a_m] = av0.w;
        As[a_c + 0][a_m + 64] = av1.x; As[a_c + 1][a_m + 64] = av1.y;
        As[a_c + 2][a_m + 64] = av1.z; As[a_c + 3][a_m + 64] = av1.w;
        *(float4*)&Bs[b_r][b_n]     = bv0;
        *(float4*)&Bs[b_r + 8][b_n] = bv1;
        __syncthreads();
        if (k0 + 16 < kend) {
            av0 = *(const float4*)(Arow0 + k0 + 16);
            av1 = *(const float4*)(Arow1 + k0 + 16);
            bv0 = *(const float4*)(Brow0 + (size_t)(k0 + 16) * N);
            bv1 = *(const float4*)(Brow1 + (size_t)(k0 + 16) * N);
        }
#pragma unroll
        for (int kk = 0; kk < 16; ++kk) {
            float4 a0 = *(const float4*)&As[kk][ty * 4];
            float4 a1 = *(const float4*)&As[kk][64 + ty * 4];
            float4 b0 = *(const float4*)&Bs[kk][tx * 4];
            float4 b1 = *(const float4*)&Bs[kk][64 + tx * 4];
            float av[8] = {a0.x, a0.y, a0.z, a0.w, a1.x, a1.y, a1.z, a1.w};
            float bv[8] = {b0.x, b0.y, b0.z, b0.w, b1.x, b1.y, b1.z, b1.w};
#pragma unroll
            for (int i = 0; i < 8; ++i)
#pragma unroll
                for (int j = 0; j < 8; ++j)
                    acc[i][j] = fmaf(av[i], bv[j], acc[i][j]);
        }
    }

#pragma unroll
    for (int i = 0; i < 8; ++i) {
        int m = bm + 4 * ty + (i & 3) + (i >> 2) * 64;
#pragma unroll
        for (int half = 0; half < 2; ++half) {
            int n0 = bn + 4 * tx + half * 64;
            size_t idx = (size_t)m * N + n0;
            float4 o;
            float* oo = (float*)&o;
#pragma unroll
            for (int j = 0; j < 4; ++j) {
                float t = acc[i][half * 4 + j];
                if (EPI != EPI_NONE && KCH == 0) t += bias[n0 + j];
                float r;
                if (KCH > 0)                 r = t;
                else if (EPI == EPI_SIGMOID) r = 1.0f / (1.0f + expf(-t));
                else if (EPI == EPI_GATERES) r = resid[idx + j] + gate[(size_t)m * gstride + n0 + j] * t;
                else if (EPI == EPI_GELU)    r = 0.5f * t * (1.0f + erff(t * 0.70710678118654752440f));
                else                         r = t;
                oo[j] = r;
            }
            *(float4*)&Cw[idx] = o;
        }
    }
}

// ---------------------------------------------------------------------------
// gelu GEMM writing 2-plane bf16 split directly (validated rounds 18/21)
// ---------------------------------------------------------------------------
__global__ __launch_bounds__(256) void k_gemm_gelu2(
    const float* __restrict__ A, const float* __restrict__ B,
    const float* __restrict__ bias,
    unsigned short* __restrict__ P0, unsigned short* __restrict__ P1,
    int M, int N, int K)
{
    __shared__ float As[16][132];
    __shared__ float Bs[16][132];
    const int tid = threadIdx.x;
    const int tx = tid & 15, ty = tid >> 4;
    const int bm = blockIdx.y * 128, bn = blockIdx.x * 128;
    float acc[8][8] = {};

    const int a_m = tid >> 2;
    const int a_c = (tid & 3) * 4;
    const int b_r = tid >> 5;
    const int b_n = (tid & 31) * 4;

    const float* Arow0 = A + (size_t)(bm + a_m) * K + a_c;
    const float* Arow1 = A + (size_t)(bm + a_m + 64) * K + a_c;
    const float* Brow0 = B + (size_t)b_r * N + bn + b_n;
    const float* Brow1 = B + (size_t)(b_r + 8) * N + bn + b_n;

    float4 av0 = *(const float4*)(Arow0);
    float4 av1 = *(const float4*)(Arow1);
    float4 bv0 = *(const float4*)(Brow0);
    float4 bv1 = *(const float4*)(Brow1);

    for (int k0 = 0; k0 < K; k0 += 16) {
        __syncthreads();
        As[a_c + 0][a_m] = av0.x; As[a_c + 1][a_m] = av0.y;
        As[a_c + 2][a_m] = av0.z; As[a_c + 3][a_m] = av0.w;
        As[a_c + 0][a_m + 64] = av1.x; As[a_c + 1][a_m + 64] = av1.y;
        As[a_c + 2][a_m + 64] = av1.z; As[a_c + 3][a_m + 64] = av1.w;
        *(float4*)&Bs[b_r][b_n]     = bv0;
        *(float4*)&Bs[b_r + 8][b_n] = bv1;
        __syncthreads();
        if (k0 + 16 < K) {
            av0 = *(const float4*)(Arow0 + k0 + 16);
            av1 = *(const float4*)(Arow1 + k0 + 16);
            bv0 = *(const float4*)(Brow0 + (size_t)(k0 + 16) * N);
            bv1 = *(const float4*)(Brow1 + (size_t)(k0 + 16) * N);
        }
#pragma unroll
        for (int kk = 0; kk < 16; ++kk) {
            float4 a0 = *(const float4*)&As[kk][ty * 4];
            float4 a1 = *(const float4*)&As[kk][64 + ty * 4];
            float4 b0 = *(const float4*)&Bs[kk][tx * 4];
            float4 b1 = *(const float4*)&Bs[kk][64 + tx * 4];
            float av[8] = {a0.x, a0.y, a0.z, a0.w, a1.x, a1.y, a1.z, a1.w};
            float bv[8] = {b0.x, b0.y, b0.z, b0.w, b1.x, b1.y, b1.z, b1.w};
#pragma unroll
            for (int i = 0; i < 8; ++i)
#pragma unroll
                for (int j = 0; j < 8; ++j)
                    acc[i][j] = fmaf(av[i], bv[j], acc[i][j]);
        }
    }

#pragma unroll
    for (int i = 0; i < 8; ++i) {
        int m = bm + 4 * ty + (i & 3) + (i >> 2) * 64;
#pragma unroll
        for (int half = 0; half < 2; ++half) {
            int n0 = bn + 4 * tx + half * 64;
            ushort4 o0, o1;
            unsigned short* q0 = (unsigned short*)&o0;
            unsigned short* q1 = (unsigned short*)&o1;
#pragma unroll
            for (int j = 0; j < 4; ++j) {
                float t = acc[i][half * 4 + j] + bias[n0 + j];
                float r = 0.5f * t * (1.0f + erff(t * 0.70710678118654752440f));
                unsigned short h0 = f2bf(r);
                q0[j] = h0; q1[j] = f2bf(r - bf2f(h0));
            }
            size_t idx = (size_t)m * N + n0;
            *(ushort4*)&P0[idx] = o0;
            *(ushort4*)&P1[idx] = o1;
        }
    }
}

// ---------------------------------------------------------------------------
// pack wq|wk|wv|wg -> wpack (512x2048), biases -> bpack
// ---------------------------------------------------------------------------
__global__ __launch_bounds__(256) void k_pack_qkvg(
    const float* __restrict__ wq, const float* __restrict__ wk,
    const float* __restrict__ wv, const float* __restrict__ wg,
    const float* __restrict__ bq, const float* __restrict__ bk,
    const float* __restrict__ bv, const float* __restrict__ bg,
    float* __restrict__ wpack, float* __restrict__ bpack)
{
    const int idx = blockIdx.x * 256 + threadIdx.x;
    const int k = idx >> 11, n = idx & 2047;
    const int sel = n >> 9, nn = n & 511;
    const float* w = (sel == 0) ? wq : (sel == 1) ? wk : (sel == 2) ? wv : wg;
    wpack[idx] = w[(size_t)k * 512 + nn];
    if (idx < 2048) {
        const float* bb = (sel == 0) ? bq : (sel == 1) ? bk : (sel == 2) ? bv : bg;
        bpack[idx] = bb[nn];
    }
}

// ---------------------------------------------------------------------------
// banded attention over packed QKVG (validated)
// ---------------------------------------------------------------------------
__global__ __launch_bounds__(256) void k_attn(
    const float* __restrict__ qkvg, float* __restrict__ out)
{
    const int w    = (blockIdx.x << 2) + (threadIdx.x >> 6);
    const int lane = threadIdx.x & 63;
    const int h = w & 3;
    const int t = (w >> 2) & 2047;
    const int b = w >> 13;
    const size_t qb = ((size_t)(b * TT + t)) * 2048 + h * DH;
    const float q0 = qkvg[qb + lane], q1 = qkvg[qb + 64 + lane];

    float s[11];
#pragma unroll
    for (int o = 0; o < 11; ++o) {
        int pos = t + o - 5;
        bool valid = (pos >= 0 && pos < TT);
        float p = 0.0f;
        if (valid) {
            size_t kb = ((size_t)(b * TT + pos)) * 2048 + 512 + h * DH;
            p = q0 * qkvg[kb + lane] + q1 * qkvg[kb + 64 + lane];
        }
        for (int off = 32; off; off >>= 1) p += __shfl_xor(p, off, 64);
        s[o] = valid ? p / sqrtf(128.0f) : -1e9f;
    }
    float m = s[0];
#pragma unroll
    for (int o = 1; o < 11; ++o) m = fmaxf(m, s[o]);
    float e[11], sum = 0.0f;
#pragma unroll
    for (int o = 0; o < 11; ++o) { e[o] = expf(s[o] - m); sum += e[o]; }

    float o0 = 0.0f, o1 = 0.0f;
#pragma unroll
    for (int o = 0; o < 11; ++o) {
        int pos = t + o - 5;
        if (pos < 0 || pos >= TT) continue;
        float a = e[o] / sum;
        size_t vb = ((size_t)(b * TT + pos)) * 2048 + 1024 + h * DH;
        o0 = fmaf(a, qkvg[vb + lane], o0);
        o1 = fmaf(a, qkvg[vb + 64 + lane], o1);
    }
    const size_t ob = ((size_t)(b * TT + t)) * DIM + h * DH;
    out[ob + lane]      = o0;
    out[ob + 64 + lane] = o1;
}

// ---------------------------------------------------------------------------
// wf2f conv (KP rows; rows >= GG zero), bias_c (validated)
// ---------------------------------------------------------------------------
__global__ __launch_bounds__(256) void k_conv_wf(
    const float* __restrict__ wf, float* __restrict__ wf2f)
{
    __shared__ float w[25];
    const int qq = blockIdx.x;
    if (qq >= GG) {
        for (int s = threadIdx.x; s < SS; s += 256)
            wf2f[(size_t)qq * SS + s] = 0.0f;
        return;
    }
    const int y = qq / 45, x = qq % 45;
    if (threadIdx.x < 25) {
        int ki = threadIdx.x / 5, kj = threadIdx.x % 5;
        double gi = exp(-0.5 * (double)((ki - 2) * (ki - 2)));
        double gj = exp(-0.5 * (double)((kj - 2) * (kj - 2)));
        double Z  = 1.0 + 2.0 * exp(-0.5) + 2.0 * exp(-2.0);
        w[threadIdx.x] = (float)(gi * gj / (Z * Z));
    }
    __syncthreads();
    for (int s = threadIdx.x; s < SS; s += 256) {
        double acc = 0.0;
#pragma unroll
        for (int dy = -2; dy <= 2; ++dy) {
            int yy = y + dy;
            if (yy < 0 || yy >= 45) continue;
#pragma unroll
            for (int dx = -2; dx <= 2; ++dx) {
                int xx2 = x + dx;
                if (xx2 < 0 || xx2 >= 45) continue;
                acc = fma((double)w[(dy + 2) * 5 + (dx + 2)],
                          (double)wf[(size_t)(yy * 45 + xx2) * SS + s], acc);
            }
        }
        wf2f[(size_t)qq * SS + s] = (float)acc;
    }
}

__global__ __launch_bounds__(256) void k_bias_c(
    const float* __restrict__ b2, const float* __restrict__ wf2f,
    float* __restrict__ c)
{
    const int s = blockIdx.x * 4 + (threadIdx.x >> 6);
    const int lane = threadIdx.x & 63;
    double acc = 0.0;
    for (int qq = lane; qq < GG; qq += 64)
        acc = fma((double)b2[qq], (double)wf2f[(size_t)qq * SS + s], acc);
    for (int off = 32; off; off >>= 1) acc += __shfl_xor(acc, off, 64);
    if (lane == 0) c[s] = (float)acc;
}

// w2 (1024xGG) -> 2-plane bf16 (1024xKP), cols >= GG zero
__global__ __launch_bounds__(256) void k_splitw2(
    const float* __restrict__ w2, unsigned short* __restrict__ P0,
    unsigned short* __restrict__ P1)
{
    const int idx = blockIdx.x * 256 + threadIdx.x;   // 1024*KP
    const int m = idx >> 11, p = idx & (KP - 1);
    float v = (p < GG) ? w2[(size_t)m * GG + p] : 0.0f;
    unsigned short h0 = f2bf(v);
    P0[idx] = h0; P1[idx] = f2bf(v - bf2f(h0));
}

// ---------------------------------------------------------------------------
// transpose + 2-plane split: W (KxN f32) -> planes (NxK bf16)  (validated)
// ---------------------------------------------------------------------------
__global__ __launch_bounds__(256) void k_tsplit2(
    const float* __restrict__ W, unsigned short* __restrict__ T0,
    unsigned short* __restrict__ T1, int K, int N)
{
    __shared__ float t[32][33];
    const int tx = threadIdx.x & 31, ty = threadIdx.x >> 5;
    const int n0 = blockIdx.x * 32, k0 = blockIdx.y * 32;
#pragma unroll
    for (int p = 0; p < 4; ++p)
        t[ty + 8 * p][tx] = W[(size_t)(k0 + ty + 8 * p) * N + n0 + tx];
    __syncthreads();
#pragma unroll
    for (int p = 0; p < 4; ++p) {
        float v = t[tx][ty + 8 * p];
        size_t o = (size_t)(n0 + ty + 8 * p) * K + k0 + tx;
        unsigned short h0 = f2bf(v);
        T0[o] = h0; T1[o] = f2bf(v - bf2f(h0));
    }
}

// ---------------------------------------------------------------------------
// bf16x4 MFMA GEMM (validated rounds 18/21). EPI_BIAS / EPI_QKVG / EPI_NONE.
// 2-plane x 2-plane, all 4 products — exact in the split (residual ~2^-18).
// 128x128 block, BK=32, 4 waves 2x2; fragment maps HW-verified (m89 C/D).
// At ~990 TF effective MFMA throughput = the documented ceiling of this
// 2-barrier-per-K-step structure (m97); next lever would be the 8-phase
// 256^2 schedule (out of risk budget this session).
// ---------------------------------------------------------------------------
template<int EPI>
__global__ __launch_bounds__(256) void k_gemm_bf16x4(
    const unsigned short* __restrict__ A0, const unsigned short* __restrict__ A1,
    const unsigned short* __restrict__ B0, const unsigned short* __restrict__ B1,
    const float* __restrict__ bias, float* __restrict__ C, int M, int N, int K)
{
    __shared__ unsigned short As[2][128][40];
    __shared__ unsigned short Bs[2][128][40];
    const int tid = threadIdx.x, lane = tid & 63, wid = tid >> 6;
    const int wm = wid >> 1, wn = wid & 1;
    const int bm = blockIdx.y * 128, bn = blockIdx.x * 128;
    const int lm = lane & 15, lk = lane >> 4;

    f32x4 acc[4][4] = {};

    const int sr = tid >> 1, sc = (tid & 1) * 16;
    const unsigned short* Ap[2] = {A0, A1};
    const unsigned short* Bp[2] = {B0, B1};

    for (int k0 = 0; k0 < K; k0 += 32) {
        const size_t ga = (size_t)(bm + sr) * K + k0 + sc;
        const size_t gb = (size_t)(bn + sr) * K + k0 + sc;
        __syncthreads();
#pragma unroll
        for (int pl = 0; pl < 2; ++pl) {
            *(uint4*)&As[pl][sr][sc]     = *(const uint4*)&Ap[pl][ga];
            *(uint4*)&As[pl][sr][sc + 8] = *(const uint4*)&Ap[pl][ga + 8];
            *(uint4*)&Bs[pl][sr][sc]     = *(const uint4*)&Bp[pl][gb];
            *(uint4*)&Bs[pl][sr][sc + 8] = *(const uint4*)&Bp[pl][gb + 8];
        }
        __syncthreads();

        short8v af[2][4], bf[2][4];
#pragma unroll
        for (int pl = 0; pl < 2; ++pl)
#pragma unroll
            for (int i = 0; i < 4; ++i) {
                af[pl][i] = *(const short8v*)&As[pl][wm * 64 + i * 16 + lm][lk * 8];
                bf[pl][i] = *(const short8v*)&Bs[pl][wn * 64 + i * 16 + lm][lk * 8];
            }
#pragma unroll
        for (int i = 0; i < 4; ++i)
#pragma unroll
            for (int j = 0; j < 4; ++j) {
                acc[i][j] = __builtin_amdgcn_mfma_f32_16x16x32_bf16(af[0][i], bf[0][j], acc[i][j], 0, 0, 0);
                acc[i][j] = __builtin_amdgcn_mfma_f32_16x16x32_bf16(af[0][i], bf[1][j], acc[i][j], 0, 0, 0);
                acc[i][j] = __builtin_amdgcn_mfma_f32_16x16x32_bf16(af[1][i], bf[0][j], acc[i][j], 0, 0, 0);
                acc[i][j] = __builtin_amdgcn_mfma_f32_16x16x32_bf16(af[1][i], bf[1][j], acc[i][j], 0, 0, 0);
            }
    }

#pragma unroll
    for (int i = 0; i < 4; ++i) {
        const int row0 = bm + wm * 64 + i * 16 + lk * 4;
#pragma unroll
        for (int j = 0; j < 4; ++j) {
            const int col = bn + wn * 64 + j * 16 + lm;
            const float bb = (EPI == EPI_NONE) ? 0.0f : bias[col];
#pragma unroll
            for (int r = 0; r < 4; ++r) {
                float t = acc[i][j][r] + bb;
                if (EPI == EPI_QKVG && col >= 1536) t = 1.0f / (1.0f + expf(-t));
                C[(size_t)(row0 + r) * N + col] = t;
            }
        }
    }
}

// ---------------------------------------------------------------------------
// top-40 one-hot, one wave per row (validated round 16)
// ---------------------------------------------------------------------------
__global__ __launch_bounds__(256) void k_topk(
    const float* __restrict__ scores, float* __restrict__ sdr)
{
    __shared__ float vals[4][64 * 33];
    const int wv = threadIdx.x >> 6;
    const int lane = threadIdx.x & 63;
    const int row = (blockIdx.x << 2) + wv;
    const float* srow = scores + (size_t)row * SS;
    float* drow = sdr + (size_t)row * SS;
    float* my = &vals[wv][lane * 33];

    float lmax = -INFINITY; int lidx = 0x7fffffff;
#pragma unroll
    for (int j = 0; j < 32; ++j) {
        const int gi = j * 64 + lane;
        float vvv = srow[gi];
        drow[gi] = 0.0f;
        vals[wv][lane * 33 + j] = vvv;
        if (vvv > lmax) { lmax = vvv; lidx = gi; }
    }

    for (int it = 0; it < KTOP; ++it) {
        float bv = lmax; int bi = lidx;
#pragma unroll
        for (int off = 32; off; off >>= 1) {
            float ov = __shfl_xor(bv, off, 64);
            int   oi = __shfl_xor(bi, off, 64);
            if (ov > bv || (ov == bv && oi < bi)) { bv = ov; bi = oi; }
        }
        if ((bi & 63) == lane) {
            drow[bi] = 1.0f;
            my[bi >> 6] = -INFINITY;
            lmax = -INFINITY; lidx = 0x7fffffff;
#pragma unroll
            for (int j = 0; j < 32; ++j) {
                float vvv = my[j];
                if (vvv > lmax) { lmax = vvv; lidx = j * 64 + lane; }
            }
        }
    }
}

// ---------------------------------------------------------------------------
// Buffer plan = round 21 (passed, 771 µs), unchanged.
// slot0: x@0; Xn0@3SZ; Xn1@3.5SZ; wpack@2.5SZ; bpack@2.5SZ+MEG;
//        Wq0@SZ, Wq1@SZ+0.5MEG; attn@SZ (over dead Wq); ctx@2SZ;
//        A0@0, A1@SZ (gelu2 out); B0@2SZ, B1@2SZ+MEG (over dead ctx);
//        cvec@3SZ (over dead Xn0); sdr@0.
// slot1: qkvg@0 (dead after gateres); wf2f@0; wfT0@SZ, wfT1@SZ+2MEG;
//        w2p0@2SZ, w2p1@2SZ+MEG; Wf@3SZ; scores@0.
// ---------------------------------------------------------------------------
extern "C" void kernel_launch(void* const* d_in, const int* in_sizes, int n_in,
                              void* d_out, int out_size, void* d_ws, size_t ws_size,
                              hipStream_t stream)
{
    (void)d_ws; (void)ws_size; (void)in_sizes; (void)n_in; (void)out_size;

    const int*   tokens = (const int*)d_in[0];
    const float* table  = (const float*)d_in[1];
    const float* ln_g   = (const float*)d_in[2];
    const float* ln_b   = (const float*)d_in[3];
    const float* wq = (const float*)d_in[4];  const float* bq = (const float*)d_in[5];
    const float* wk = (const float*)d_in[6];  const float* bk = (const float*)d_in[7];
    const float* wv = (const float*)d_in[8];  const float* bv = (const float*)d_in[9];
    const float* wo = (const float*)d_in[10]; const float* bo = (const float*)d_in[11];
    const float* wg = (const float*)d_in[12]; const float* bg = (const float*)d_in[13];
    const float* w1 = (const float*)d_in[14]; const float* b1 = (const float*)d_in[15];
    const float* w2 = (const float*)d_in[16]; const float* b2 = (const float*)d_in[17];
    const float* wf = (const float*)d_in[18];

    const size_t SZ  = (size_t)NROW * DIM;         // 4,194,304 floats
    const size_t HSZ = SZ / 2;
    const size_t MEG = 1u << 20;                   // 1,048,576 floats
    float* slot0 = (float*)d_out;
    float* slot1 = slot0 + (size_t)NROW * SS;

    float* x     = slot0;
    unsigned short* Xn0 = (unsigned short*)(slot0 + 3 * SZ);
    unsigned short* Xn1 = (unsigned short*)(slot0 + 3 * SZ + HSZ);
    float* wpack = slot0 + 2 * SZ + HSZ;
    float* bpack = wpack + MEG;
    unsigned short* Wq0 = (unsigned short*)(slot0 + SZ);
    unsigned short* Wq1 = (unsigned short*)(slot0 + SZ + MEG / 2);
    float* attn  = slot0 + SZ;
    float* ctx   = slot0 + 2 * SZ;
    unsigned short* A0 = (unsigned short*)(slot0);
    unsigned short* A1 = (unsigned short*)(slot0 + SZ);
    unsigned short* B0 = (unsigned short*)(slot0 + 2 * SZ);
    unsigned short* B1 = (unsigned short*)(slot0 + 2 * SZ + MEG);
    float* cvec = slot0 + 3 * SZ;

    float* qkvg  = slot1;
    float* wf2f  = slot1;                          // KPx2048 = SZ floats
    unsigned short* wfT0 = (unsigned short*)(slot1 + SZ);
    unsigned short* wfT1 = (unsigned short*)(slot1 + SZ + 2 * MEG);
    unsigned short* w2p0 = (unsigned short*)(slot1 + 2 * SZ);
    unsigned short* w2p1 = (unsigned short*)(slot1 + 2 * SZ + MEG);
    float* Wf    = slot1 + 3 * SZ;                 // 1024x2048 f32
    float* scores = slot1;
    float* sdr    = slot0;

    dim3 blk(256);

    k_embed_ln<<<NROW, blk, 0, stream>>>(tokens, table, ln_g, ln_b, x, Xn0, Xn1);
    k_pack_qkvg<<<4096, blk, 0, stream>>>(wq, wk, wv, wg, bq, bk, bv, bg, wpack, bpack);
    k_tsplit2               <<<dim3(64, 16), blk, 0, stream>>>(wpack, Wq0, Wq1, 512, 2048);
    k_gemm_bf16x4<EPI_QKVG> <<<dim3(16, 64), blk, 0, stream>>>(Xn0, Xn1, Wq0, Wq1, bpack, qkvg, NROW, 2048, DIM);
    k_attn                  <<<NROW, blk, 0, stream>>>(qkvg, attn);
    k_gemm_f32<EPI_GATERES> <<<dim3(4, 64), blk, 0, stream>>>(attn, wo, bo, ctx, NROW, DIM, DIM, x, qkvg + 1536, 2048);
    k_gemm_gelu2            <<<dim3(8, 64), blk, 0, stream>>>(ctx, w1, b1, A0, A1, NROW, 2 * DIM, DIM);
    k_conv_wf               <<<KP,   blk, 0, stream>>>(wf, wf2f);
    k_splitw2               <<<(1024 * KP) / 256, blk, 0, stream>>>(w2, w2p0, w2p1);
    k_tsplit2               <<<dim3(64, 64), blk, 0, stream>>>(wf2f, wfT0, wfT1, KP, 2048);
    k_gemm_bf16x4<EPI_NONE> <<<dim3(16, 8), blk, 0, stream>>>(w2p0, w2p1, wfT0, wfT1, cvec, Wf, 1024, SS, KP);
    k_bias_c                <<<SS / 4, blk, 0, stream>>>(b2, wf2f, cvec);
    k_tsplit2               <<<dim3(64, 32), blk, 0, stream>>>(Wf, B0, B1, 1024, SS);
    k_gemm_bf16x4<EPI_BIAS> <<<dim3(16, 64), blk, 0, stream>>>(A0, A1, B0, B1, cvec, scores, NROW, SS, 1024);
    k_topk                  <<<2048, blk, 0, stream>>>(scores, sdr);
}